// Round 21
// baseline (323.822 us; speedup 1.0000x reference)
//
#include <hip/hip_runtime.h>
#include <math.h>

typedef short  bf16x8 __attribute__((ext_vector_type(8)));
typedef float  f32x4  __attribute__((ext_vector_type(4)));

#define DIM   1024
#define RANK  256
#define NROWS 16
#define NT    1024
#define NWAVE 16
#define TOTAL_ROWS 4096
#define OUT_HALF (TOTAL_ROWS*DIM)

// LDS byte layout (107.6 KB, single 1024-thread block/CU -> 16 waves/CU)
#define VS_OFF    0           // ushort[16][1024] swizzled: v / gamma / v'
#define H2_OFF    32768       // ushort[16][256] swizzled
#define STAGE_OFF 40960       // 4 slots x 16 KB staging ring (65536)
#define WS_OFF    106496      // float[16][16]
#define SG_OFF    107520      // float[16]
#define SMEM_BYTES 107584

static constexpr double XI  = 0.1786178958448091;
static constexpr double LAM = -0.2123418310626054;
static constexpr double CHI = -0.0662645826698185;

typedef __attribute__((address_space(1))) void as1_void;
typedef __attribute__((address_space(3))) void as3_void;

#define WAITV(n) asm volatile("s_waitcnt vmcnt(" #n ")" ::: "memory")

// phase barrier: LDS ops drained, global_load_lds stream stays in flight
__device__ __forceinline__ void bbar() {
    asm volatile("s_waitcnt lgkmcnt(0)" ::: "memory");
    __builtin_amdgcn_s_barrier();
}

__device__ __forceinline__ unsigned short f2bf(float f) {
    unsigned u = __builtin_bit_cast(unsigned, f);
    u += 0x7FFFu + ((u >> 16) & 1u);        // round-to-nearest-even
    return (unsigned short)(u >> 16);
}
__device__ __forceinline__ float bf2f(unsigned short b) {
    return __builtin_bit_cast(float, ((unsigned)b) << 16);
}

// swizzle: byte ^= (row&7)<<4
__device__ __forceinline__ int vs_addr(int m, int kb) {
    return VS_OFF + ((m * 2048 + kb) ^ ((m & 7) << 4));
}
__device__ __forceinline__ int h2_addr(int m, int kb) {
    return H2_OFF + ((m * 512 + kb) ^ ((m & 7) << 4));
}

// issue this wave's 1 frag (position w) of stream batch sb into the ring.
// Wave-private. DEPTH-3 WAR invariant (proven R16/R20): called AFTER batch
// b's MFMA (+ sched_barrier pin), sb=b+3 writes slot (b-1)&3, whose ds_read
// was retired by the lgkm wait before batch b-1's MFMA. The sched_barrier
// stops hipcc sinking the register-only MFMA (and its lgkm wait) below the
// issue — the R17 failure (guide rule #18).
__device__ __forceinline__ void issue1(const char* pkb, char* smem_, int sb, int w, int lane) {
    char* dst = smem_ + STAGE_OFF + (sb & 3) * 16384 + w * 1024;
    const char* g = pkb + (size_t)(((unsigned)(sb * 16 + w)) << 10) + lane * 16;
    __builtin_amdgcn_global_load_lds((const as1_void*)g, (as3_void*)dst, 16, 0, 0);
}

// ---- prep: pack U,W into the bf16 consumption-order STREAM (64 batches x 16 KB).
// Batch b<32 (H, kt=b): frag j = U-frag(kt=b, nt=j)           (j = wave id)
// Batch 32+u (G): p=u>>3, kk=u&7; frag j = W-frag(kt=kk, nt=p*16+j).
// B-frag 16x16x32: lane l holds B[k = kt*32 + (l>>4)*8 + jj][n = nt*16 + (l&15)]
__global__ __launch_bounds__(256)
void prep_pack(const float* __restrict__ U, const float* __restrict__ Wm,
               bf16x8* __restrict__ pk)
{
    const int tid  = blockIdx.x * 256 + threadIdx.x;   // 0..65535
    const int lane = tid & 63;
    const int frag = tid >> 6;                          // 0..1023
    bf16x8 o;
    if (frag < 512) {
        const int kt = frag >> 4, nt = frag & 15;
        const int krow = kt * 32 + (lane >> 4) * 8;
        const int n    = nt * 16 + (lane & 15);
        #pragma unroll
        for (int j = 0; j < 8; ++j) o[j] = (short)f2bf(U[(krow + j) * RANK + n]);
    } else {
        const int idx = frag - 512;                     // 0..511
        const int u   = idx >> 4;                       // 0..31
        const int j   = idx & 15;
        const int p   = u >> 3, kk = u & 7;
        const int nt  = p * 16 + j;
        const int krow = kk * 32 + (lane >> 4) * 8;
        const int n    = nt * 16 + (lane & 15);
        #pragma unroll
        for (int jj = 0; jj < 8; ++jj) o[jj] = (short)f2bf(Wm[(krow + jj) * DIM + n]);
    }
    pk[frag * 64 + lane] = o;
}

__global__ __launch_bounds__(NT)
void omelyan_mfma(const float* __restrict__ x_in,
                  const float* __restrict__ v_in,
                  const float* __restrict__ force,
                  const float* __restrict__ Vw,
                  const int* __restrict__ steps_p,
                  const bf16x8* __restrict__ pk,
                  float* __restrict__ out)
{
    extern __shared__ char smem[];
    float* wsums = (float*)(smem + WS_OFF);
    float* sings = (float*)(smem + SG_OFF);
    const char* pkb = (const char*)pk;

    const int t    = threadIdx.x;        // 0..1023
    const int lane = t & 63;
    const int w    = t >> 6;             // 0..15
    const int row0 = blockIdx.x * NROWS;
    const int nsteps = steps_p[0];

    const float dt = 0.01f;

    // per-thread state: element (m, d = t) — 33 regs, fits the 64-VGPR cap
    float xr[NROWS], vr[NROWS];
    const float vw = Vw[t];

    #pragma unroll
    for (int m = 0; m < NROWS; ++m) {
        const int base = (row0 + m) * DIM + t;
        xr[m] = x_in[base];
        vr[m] = v_in[base];
        *(unsigned short*)(smem + vs_addr(m, 2 * t)) = f2bf(vr[m]);
    }
    __syncthreads();    // clean vmcnt base

    // prime the stream: batches 0..2 (depth 3 -> 3 loads/wave in flight)
    issue1(pkb, smem, 0, w, lane);
    issue1(pkb, smem, 1, w, lane);
    issue1(pkb, smem, 2, w, lane);

    #pragma unroll 1
    for (int step = 0; step < nsteps; ++step) {
        #pragma unroll 1
        for (int sub = 0; sub < 4; ++sub) {
            const float cdt = dt * (sub == 0 ? (float)XI :
                                    sub == 1 ? (float)CHI :
                                    sub == 2 ? (float)(1.0 - 2.0 * (CHI + XI)) :
                                               (float)CHI);
            const float ddt = dt * ((sub == 0 || sub == 3)
                                    ? (float)((1.0 - 2.0 * LAM) * 0.5)
                                    : (float)LAM);

            // ---- drift x + r2 reduce -> wsums ----
            #pragma unroll
            for (int m = 0; m < NROWS; ++m) {
                xr[m] = fmaf(cdt, vr[m], xr[m]);
                float s = xr[m] * xr[m];
                #pragma unroll
                for (int off = 32; off >= 1; off >>= 1) s += __shfl_xor(s, off, 64);
                if (lane == 0) wsums[m * NWAVE + w] = s;
            }
            bbar();                         // b_A: prior kick's vs + wsums visible
            if (t < NROWS) {
                float r2 = 0.f;
                #pragma unroll
                for (int q = 0; q < NWAVE; ++q) r2 += wsums[t * NWAVE + q];
                sings[t] = 1.f + exp2f(-r2 * 1.4426950408889634f);
            }

            // ---- H: batches 0..31 (wave w owns nt = w) ----
            {
                f32x4 hacc = {0.f, 0.f, 0.f, 0.f};
                #pragma unroll 2
                for (int ks = 0; ks < 32; ++ks) {
                    WAITV(2);                // own load for batch ks retired
                    const bf16x8 a = *(const bf16x8*)(smem + vs_addr(lane & 15, ks * 64 + (lane >> 4) * 16));
                    const bf16x8 f = *(const bf16x8*)(smem + STAGE_OFF + (ks & 3) * 16384 + w * 1024 + lane * 16);
                    hacc = __builtin_amdgcn_mfma_f32_16x16x32_bf16(a, f, hacc, 0, 0, 0);
                    __builtin_amdgcn_sched_barrier(0);   // pin MFMA+lgkm above issue
                    issue1(pkb, smem, (ks + 3) & 63, w, lane);   // writes slot (ks-1)&3
                }
                // h2 = h*h (bf16, swizzled); D: col=lane&15, row=(lane>>4)*4+r
                #pragma unroll
                for (int r = 0; r < 4; ++r) {
                    const int m = (lane >> 4) * 4 + r;
                    const int n = w * 16 + (lane & 15);
                    *(unsigned short*)(smem + h2_addr(m, 2 * n)) = f2bf(hacc[r] * hacc[r]);
                }
            }
            bbar();                         // b_B: h2 visible

            // ---- G: 4 passes; pass p: wave w owns nt = p*16 + w ----
            #pragma unroll 1
            for (int p = 0; p < 4; ++p) {
                f32x4 g = {0.f, 0.f, 0.f, 0.f};
                #pragma unroll 2
                for (int kk = 0; kk < 8; ++kk) {
                    const int b = 32 + p * 8 + kk;
                    WAITV(2);
                    const bf16x8 a = *(const bf16x8*)(smem + h2_addr(lane & 15, kk * 64 + (lane >> 4) * 16));
                    const bf16x8 f = *(const bf16x8*)(smem + STAGE_OFF + (b & 3) * 16384 + w * 1024 + lane * 16);
                    g = __builtin_amdgcn_mfma_f32_16x16x32_bf16(a, f, g, 0, 0, 0);
                    __builtin_amdgcn_sched_barrier(0);
                    issue1(pkb, smem, (b + 3) & 63, w, lane);  // wraps to next accel's 0..2
                }
                // gamma (bf16) into dead vs cells, cols (p*16+w)*16+c (wave-exclusive)
                #pragma unroll
                for (int r = 0; r < 4; ++r) {
                    const int m = (lane >> 4) * 4 + r;
                    const int n = (p * 16 + w) * 16 + (lane & 15);
                    *(unsigned short*)(smem + vs_addr(m, 2 * n)) = f2bf(g[r]);
                }
            }
            bbar();                                     // b_C: gamma visible

            // ---- kick: read gamma from vs cells, write v' back to same cells ----
            #pragma unroll
            for (int m = 0; m < NROWS; ++m) {
                const float fm = force[(row0 + m) * DIM + t];
                const float gmm = bf2f(*(const unsigned short*)(smem + vs_addr(m, 2 * t)));
                const float sing = sings[m];
                const float z  = xr[m] * vw;
                const float e  = exp2f(z * 2.885390081777927f);   // e^(2z)
                const float th = 1.f - 2.f / (e + 1.f);           // tanh(z)
                const float gate = fmaf(0.1f, th, 1.f);
                const float a = fm - gmm * gate * sing;
                vr[m] = fmaf(ddt, a, vr[m]);
                *(unsigned short*)(smem + vs_addr(m, 2 * t)) = f2bf(vr[m]);  // same-thread RMW
            }
            // next accel's b_A covers these vs writes
        } // sub

        // final drift: x += C5*dt*v
        const float c5dt = dt * (float)XI;
        #pragma unroll
        for (int m = 0; m < NROWS; ++m)
            xr[m] = fmaf(c5dt, vr[m], xr[m]);
    } // step

    __syncthreads();    // drain dangling prefetches before store

    // ---- store (x, v) ----
    #pragma unroll
    for (int m = 0; m < NROWS; ++m) {
        const int base = (row0 + m) * DIM + t;
        out[base] = xr[m];
        out[OUT_HALF + base] = vr[m];
    }
}

extern "C" void kernel_launch(void* const* d_in, const int* in_sizes, int n_in,
                              void* d_out, int out_size, void* d_ws, size_t ws_size,
                              hipStream_t stream) {
    const float* x_in  = (const float*)d_in[0];
    const float* v_in  = (const float*)d_in[1];
    const float* force = (const float*)d_in[2];
    const float* Umat  = (const float*)d_in[3];
    const float* Wmat  = (const float*)d_in[4];
    const float* Vw    = (const float*)d_in[5];
    const int*   steps = (const int*)d_in[6];
    float* out = (float*)d_out;
    bf16x8* pk = (bf16x8*)d_ws;   // 1 MiB stream

    (void)hipFuncSetAttribute((const void*)omelyan_mfma,
                              hipFuncAttributeMaxDynamicSharedMemorySize,
                              SMEM_BYTES);

    prep_pack<<<dim3(256), dim3(256), 0, stream>>>(Umat, Wmat, pk);
    omelyan_mfma<<<dim3(TOTAL_ROWS / NROWS), dim3(NT), SMEM_BYTES, stream>>>(
        x_in, v_in, force, Vw, steps, pk, out);
}